// Round 1
// baseline (3640.028 us; speedup 1.0000x reference)
//
#include <hip/hip_runtime.h>

#define IN_C 300
#define OUT_C 200
#define NEG_SLOPE 0.2f

// W-stationary GEMM geometry
#define BMB 40   // rows per block (4 waves x 10)
#define BMW 10   // rows per wave
#define BKC 20   // K chunk (divides 300 and 200)

static inline int cdiv(long a, int b) { return (int)((a + b - 1) / b); }

// ---------------- utility ----------------
__global__ __launch_bounds__(256)
void zero_int_kernel(int* __restrict__ p, int n) {
  int i = blockIdx.x * blockDim.x + threadIdx.x;
  if (i < n) p[i] = 0;
}

__device__ __forceinline__ void edge_sd(const int* __restrict__ src,
                                        const int* __restrict__ dst,
                                        int i, int E, int& s, int& d) {
  if (i < E) { s = src[i]; d = dst[i]; } else { s = d = i - E; }
}

// ---------------- CSR build ----------------
__global__ __launch_bounds__(256)
void hist_kernel(const int* __restrict__ src, const int* __restrict__ dst,
                 int E, int ET, int* __restrict__ counts) {
  int i = blockIdx.x * blockDim.x + threadIdx.x;
  if (i >= ET) return;
  int s, d; edge_sd(src, dst, i, E, s, d);
  atomicAdd(counts + d, 1);
}

// inclusive scan, 1024 elems/block (256 thr x 4). out = rowptr+1.
__global__ __launch_bounds__(256)
void scan_a_kernel(const int* __restrict__ in, int n, int* __restrict__ out,
                   int* __restrict__ bsums) {
  __shared__ int lds[256];
  int t = threadIdx.x;
  int base = blockIdx.x * 1024 + t * 4;
  int v0 = (base + 0 < n) ? in[base + 0] : 0;
  int v1 = (base + 1 < n) ? in[base + 1] : 0;
  int v2 = (base + 2 < n) ? in[base + 2] : 0;
  int v3 = (base + 3 < n) ? in[base + 3] : 0;
  int s1 = v0 + v1, s2 = s1 + v2, s3 = s2 + v3;
  lds[t] = s3;
  __syncthreads();
  for (int o = 1; o < 256; o <<= 1) {
    int x = (t >= o) ? lds[t - o] : 0;
    __syncthreads();
    lds[t] += x;
    __syncthreads();
  }
  int pre = (t > 0) ? lds[t - 1] : 0;
  if (base + 0 < n) out[base + 0] = pre + v0;
  if (base + 1 < n) out[base + 1] = pre + s1;
  if (base + 2 < n) out[base + 2] = pre + s2;
  if (base + 3 < n) out[base + 3] = pre + s3;
  if (t == 255) bsums[blockIdx.x] = lds[255];
}

// single-block inclusive scan of block sums (nb <= 256)
__global__ __launch_bounds__(256)
void scan_b_kernel(int* __restrict__ bs, int nb) {
  __shared__ int lds[256];
  int t = threadIdx.x;
  lds[t] = (t < nb) ? bs[t] : 0;
  __syncthreads();
  for (int o = 1; o < 256; o <<= 1) {
    int x = (t >= o) ? lds[t - o] : 0;
    __syncthreads();
    lds[t] += x;
    __syncthreads();
  }
  if (t < nb) bs[t] = lds[t];
}

__global__ __launch_bounds__(256)
void scan_c_kernel(int* __restrict__ out, int n, const int* __restrict__ bs) {
  int i = blockIdx.x * blockDim.x + threadIdx.x;
  if (i >= n) return;
  int b = i >> 10;
  if (b > 0) out[i] += bs[b - 1];
}

__global__ __launch_bounds__(256)
void fill_kernel(const int* __restrict__ src, const int* __restrict__ dst,
                 int E, int ET, const int* __restrict__ rowptr,
                 int* __restrict__ cursor, int* __restrict__ csr_src) {
  int i = blockIdx.x * blockDim.x + threadIdx.x;
  if (i >= ET) return;
  int s, d; edge_sd(src, dst, i, E, s, d);
  int pos = rowptr[d] + atomicAdd(cursor + d, 1);
  csr_src[pos] = s;
}

// ---------------- dense projection + fused alpha dot-products ----------------
// H[N,OUT_C] = A[N,K] @ W[K,OUT_C]; asN = H.a_src; adN = H.a_dst.
// 256 threads = 4 waves. Lane owns 4 cols (lane*4 in a 256-padded col space,
// W LDS tile zero-padded). Wave owns 10 rows; A-values are same-address LDS
// broadcasts (conflict-free, ~free BW); W read once per k, reused 10 rows.
// Next K-chunk is prefetched into registers during compute (latency hidden).
__global__ __launch_bounds__(256, 4)
void gemm_ws_kernel(const float* __restrict__ A, const float* __restrict__ W,
                    const float* __restrict__ a_src, const float* __restrict__ a_dst,
                    float* __restrict__ H, float* __restrict__ asN,
                    float* __restrict__ adN, int K, int N) {
  __shared__ float As[BMB][BKC];    // 3.2 KB
  __shared__ float Ws[BKC][256];    // 20 KB (cols 200..255 zero)
  int t = threadIdx.x;
  int wave = t >> 6, lane = t & 63;
  int col = lane * 4;               // padded col space
  long row0 = (long)blockIdx.x * BMB;
  int wrow = wave * BMW;

  // staging slot assignment
  const bool hasA = t < BMB * (BKC / 4);      // 200 float4 slots for A tile
  const int ar = t / (BKC / 4), ac = t % (BKC / 4);

  float4 pw[5];                                // W prefetch: 5 float4/thread
  float4 pa;                                   // A prefetch: 1 float4/thread

  auto loadchunk = [&](int kc) {
    #pragma unroll
    for (int i = 0; i < 5; ++i) {
      int idx = t + i * 256;                   // [0, 1280)
      int r = idx >> 6, cs = idx & 63;
      int c = cs * 4;
      if (c < OUT_C)
        pw[i] = *(const float4*)(W + (long)(kc + r) * OUT_C + c);
      else
        pw[i] = make_float4(0.f, 0.f, 0.f, 0.f);
    }
    if (hasA) {
      long rr = row0 + ar; if (rr >= N) rr = N - 1;   // clamp (last block)
      pa = *(const float4*)(A + rr * K + kc + ac * 4);
    }
  };
  auto storechunk = [&]() {
    #pragma unroll
    for (int i = 0; i < 5; ++i) {
      int idx = t + i * 256;
      int r = idx >> 6, cs = idx & 63;
      *(float4*)&Ws[r][cs * 4] = pw[i];
    }
    if (hasA) *(float4*)&As[ar][ac * 4] = pa;
  };

  float4 acc[BMW];
  #pragma unroll
  for (int r = 0; r < BMW; ++r) acc[r] = make_float4(0.f, 0.f, 0.f, 0.f);

  const int nch = K / BKC;
  loadchunk(0);
  for (int ch = 0; ch < nch; ++ch) {
    storechunk();
    __syncthreads();
    if (ch + 1 < nch) loadchunk((ch + 1) * BKC);   // in flight during compute
    #pragma unroll
    for (int kk = 0; kk < BKC; kk += 4) {
      float4 w0 = *(float4*)&Ws[kk + 0][col];
      float4 w1 = *(float4*)&Ws[kk + 1][col];
      float4 w2 = *(float4*)&Ws[kk + 2][col];
      float4 w3 = *(float4*)&Ws[kk + 3][col];
      #pragma unroll
      for (int r = 0; r < BMW; ++r) {
        float4 a = *(float4*)&As[wrow + r][kk];   // wave-uniform broadcast
        acc[r].x += a.x * w0.x + a.y * w1.x + a.z * w2.x + a.w * w3.x;
        acc[r].y += a.x * w0.y + a.y * w1.y + a.z * w2.y + a.w * w3.y;
        acc[r].z += a.x * w0.z + a.y * w1.z + a.z * w2.z + a.w * w3.z;
        acc[r].w += a.x * w0.w + a.y * w1.w + a.z * w2.w + a.w * w3.w;
      }
    }
    __syncthreads();
  }

  // epilogue: H rows + fused alpha dot-products
  if (col < OUT_C) {
    #pragma unroll
    for (int r = 0; r < BMW; ++r) {
      long grow = row0 + wrow + r;
      if (grow < N) *(float4*)(H + grow * OUT_C + col) = acc[r];
    }
  }
  float4 vs, vd;
  if (col < OUT_C) {
    vs = *(const float4*)(a_src + col);
    vd = *(const float4*)(a_dst + col);
  } else {
    vs = make_float4(0.f, 0.f, 0.f, 0.f);
    vd = make_float4(0.f, 0.f, 0.f, 0.f);
  }
  #pragma unroll
  for (int r = 0; r < BMW; ++r) {
    float ss = acc[r].x * vs.x + acc[r].y * vs.y + acc[r].z * vs.z + acc[r].w * vs.w;
    float sd = acc[r].x * vd.x + acc[r].y * vd.y + acc[r].z * vd.z + acc[r].w * vd.w;
    #pragma unroll
    for (int o = 32; o > 0; o >>= 1) {
      ss += __shfl_xor(ss, o);
      sd += __shfl_xor(sd, o);
    }
    long grow = row0 + wrow + r;
    if (lane == 0 && grow < N) { asN[grow] = ss; adN[grow] = sd; }
  }
}

// ---------------- fused segment-softmax + gather-aggregate + bias + relu ----
// One wave per destination node.
__global__ __launch_bounds__(256)
void gather_agg_kernel(const float* __restrict__ h, const float* __restrict__ asN,
                       const float* __restrict__ adN, const int* __restrict__ rowptr,
                       const int* __restrict__ csr_src, const float* __restrict__ bias,
                       float* __restrict__ out, int N) {
  int wid = (int)(((long)blockIdx.x * blockDim.x + threadIdx.x) >> 6);
  int lane = threadIdx.x & 63;
  if (wid >= N) return;
  int start = rowptr[wid], end = rowptr[wid + 1];
  float ad = adN[wid];

  // pass 1a: max over incoming edges
  float m = -1e30f;
  for (int j = start + lane; j < end; j += 64) {
    float sc = asN[csr_src[j]] + ad;
    sc = sc > 0.f ? sc : NEG_SLOPE * sc;
    m = fmaxf(m, sc);
  }
  for (int o = 32; o > 0; o >>= 1) m = fmaxf(m, __shfl_xor(m, o));
  // pass 1b: sum of exp
  float se = 0.f;
  for (int j = start + lane; j < end; j += 64) {
    float sc = asN[csr_src[j]] + ad;
    sc = sc > 0.f ? sc : NEG_SLOPE * sc;
    se += __expf(sc - m);
  }
  for (int o = 32; o > 0; o >>= 1) se += __shfl_xor(se, o);
  float inv = 1.0f / se;

  // pass 2: weighted gather-accumulate (all lanes walk edges together)
  float acc0 = 0.f, acc1 = 0.f, acc2 = 0.f, acc3 = 0.f;
  int c0 = lane, c1 = lane + 64, c2 = lane + 128, c3 = lane + 192;
  for (int j = start; j < end; ++j) {
    int s = csr_src[j];                 // broadcast read
    float sc = asN[s] + ad;
    sc = sc > 0.f ? sc : NEG_SLOPE * sc;
    float w = __expf(sc - m) * inv;
    const float* hrow = h + (long)s * OUT_C;
    acc0 += w * hrow[c0];
    acc1 += w * hrow[c1];
    acc2 += w * hrow[c2];
    if (c3 < OUT_C) acc3 += w * hrow[c3];
  }
  float* orow = out + (long)wid * OUT_C;
  orow[c0] = fmaxf(acc0 + bias[c0], 0.f);
  orow[c1] = fmaxf(acc1 + bias[c1], 0.f);
  orow[c2] = fmaxf(acc2 + bias[c2], 0.f);
  if (c3 < OUT_C) orow[c3] = fmaxf(acc3 + bias[c3], 0.f);
}

// ---------------- driver ----------------
static void run_layer(const float* xin, int K, const float* W,
                      const float* a_s, const float* a_d, const float* b,
                      const int* rowptr, const int* csr_src, int N,
                      float* hbuf, float* asN, float* adN, float* outbuf,
                      hipStream_t stream) {
  gemm_ws_kernel<<<cdiv(N, BMB), 256, 0, stream>>>(xin, W, a_s, a_d,
                                                   hbuf, asN, adN, K, N);
  gather_agg_kernel<<<cdiv((long)N * 64, 256), 256, 0, stream>>>(
      hbuf, asN, adN, rowptr, csr_src, b, outbuf, N);
}

extern "C" void kernel_launch(void* const* d_in, const int* in_sizes, int n_in,
                              void* d_out, int out_size, void* d_ws, size_t ws_size,
                              hipStream_t stream) {
  const float* x   = (const float*)d_in[0];
  const float* W0  = (const float*)d_in[1];
  const float* as0 = (const float*)d_in[2];
  const float* ad0 = (const float*)d_in[3];
  const float* b0  = (const float*)d_in[4];
  const float* W1  = (const float*)d_in[5];
  const float* as1 = (const float*)d_in[6];
  const float* ad1 = (const float*)d_in[7];
  const float* b1  = (const float*)d_in[8];
  const int*   ei  = (const int*)d_in[9];

  const int N  = in_sizes[0] / IN_C;
  const int E  = in_sizes[9] / 2;
  const int ET = E + N;
  const int* src = ei;
  const int* dst = ei + E;

  float* out = (float*)d_out;

  char* ws = (char*)d_ws;
  float* hbuf   = (float*)ws;                                  // N*OUT_C
  float* asN    = (float*)(ws + (size_t)N * OUT_C * 4);        // N
  float* adN    = asN + N;                                     // N
  int*   rowptr = (int*)(adN + N);                             // N+1
  int*   counts = rowptr + (N + 1);                            // N (also cursor)
  int*   bsums  = counts + N;                                  // 256
  int*   csrsrc = bsums + 256;                                 // ET

  const int nb = cdiv(N, 1024);

  // ---- one-time CSR build (shared by both layers) ----
  zero_int_kernel<<<cdiv(N, 256), 256, 0, stream>>>(counts, N);
  hist_kernel<<<cdiv(ET, 256), 256, 0, stream>>>(src, dst, E, ET, counts);
  scan_a_kernel<<<nb, 256, 0, stream>>>(counts, N, rowptr + 1, bsums);
  scan_b_kernel<<<1, 256, 0, stream>>>(bsums, nb);
  scan_c_kernel<<<cdiv(N, 256), 256, 0, stream>>>(rowptr + 1, N, bsums);
  zero_int_kernel<<<1, 256, 0, stream>>>(rowptr, 1);
  zero_int_kernel<<<cdiv(N, 256), 256, 0, stream>>>(counts, N);  // reuse as cursor
  fill_kernel<<<cdiv(ET, 256), 256, 0, stream>>>(src, dst, E, ET, rowptr, counts, csrsrc);

  // ---- layer 0: x -> out ----
  run_layer(x, IN_C, W0, as0, ad0, b0, rowptr, csrsrc, N, hbuf, asN, adN, out, stream);
  // ---- layer 1: out -> out (gemm reads out before gather_agg rewrites it) ----
  run_layer(out, OUT_C, W1, as1, ad1, b1, rowptr, csrsrc, N, hbuf, asN, adN, out, stream);
}

// Round 2
// 1321.337 us; speedup vs baseline: 2.7548x; 2.7548x over previous
//
#include <hip/hip_runtime.h>

#define IN_C 300
#define OUT_C 200
#define NEG_SLOPE 0.2f

// W-stationary GEMM geometry
#define BMB 64   // rows per block (4 waves x 16)
#define BMW 16   // rows per wave
#define BKC 20   // K chunk (divides 300 and 200)

static inline int cdiv(long a, int b) { return (int)((a + b - 1) / b); }

// async global->LDS, 16B per lane. LDS dest = wave-uniform base + lane*16.
__device__ __forceinline__ void glds16(const float* g, float* l) {
  __builtin_amdgcn_global_load_lds(
      (const __attribute__((address_space(1))) void*)g,
      (__attribute__((address_space(3))) void*)l, 16, 0, 0);
}

// ---------------- utility ----------------
__global__ __launch_bounds__(256)
void zero_int_kernel(int* __restrict__ p, int n) {
  int i = blockIdx.x * blockDim.x + threadIdx.x;
  if (i < n) p[i] = 0;
}

__device__ __forceinline__ void edge_sd(const int* __restrict__ src,
                                        const int* __restrict__ dst,
                                        int i, int E, int& s, int& d) {
  if (i < E) { s = src[i]; d = dst[i]; } else { s = d = i - E; }
}

// pad W[K][200] -> Wpad[K][256] (cols 200..255 zero) for exact 1KB wave-issues
__global__ __launch_bounds__(256)
void padw_kernel(const float* __restrict__ W, float* __restrict__ Wpad, int K) {
  int idx = blockIdx.x * blockDim.x + threadIdx.x;  // float4 index over K*64
  if (idx >= K * 64) return;
  int k = idx >> 6, c = (idx & 63) * 4;
  float4 v = make_float4(0.f, 0.f, 0.f, 0.f);
  if (c < OUT_C) v = *(const float4*)(W + (long)k * OUT_C + c);
  *(float4*)(Wpad + (long)k * 256 + c) = v;
}

// ---------------- CSR build ----------------
__global__ __launch_bounds__(256)
void hist_kernel(const int* __restrict__ src, const int* __restrict__ dst,
                 int E, int ET, int* __restrict__ counts) {
  int i = blockIdx.x * blockDim.x + threadIdx.x;
  if (i >= ET) return;
  int s, d; edge_sd(src, dst, i, E, s, d);
  atomicAdd(counts + d, 1);
}

// inclusive scan, 1024 elems/block (256 thr x 4). out = rowptr+1.
__global__ __launch_bounds__(256)
void scan_a_kernel(const int* __restrict__ in, int n, int* __restrict__ out,
                   int* __restrict__ bsums) {
  __shared__ int lds[256];
  int t = threadIdx.x;
  int base = blockIdx.x * 1024 + t * 4;
  int v0 = (base + 0 < n) ? in[base + 0] : 0;
  int v1 = (base + 1 < n) ? in[base + 1] : 0;
  int v2 = (base + 2 < n) ? in[base + 2] : 0;
  int v3 = (base + 3 < n) ? in[base + 3] : 0;
  int s1 = v0 + v1, s2 = s1 + v2, s3 = s2 + v3;
  lds[t] = s3;
  __syncthreads();
  for (int o = 1; o < 256; o <<= 1) {
    int x = (t >= o) ? lds[t - o] : 0;
    __syncthreads();
    lds[t] += x;
    __syncthreads();
  }
  int pre = (t > 0) ? lds[t - 1] : 0;
  if (base + 0 < n) out[base + 0] = pre + v0;
  if (base + 1 < n) out[base + 1] = pre + s1;
  if (base + 2 < n) out[base + 2] = pre + s2;
  if (base + 3 < n) out[base + 3] = pre + s3;
  if (t == 255) bsums[blockIdx.x] = lds[255];
}

// single-block inclusive scan of block sums (nb <= 256)
__global__ __launch_bounds__(256)
void scan_b_kernel(int* __restrict__ bs, int nb) {
  __shared__ int lds[256];
  int t = threadIdx.x;
  lds[t] = (t < nb) ? bs[t] : 0;
  __syncthreads();
  for (int o = 1; o < 256; o <<= 1) {
    int x = (t >= o) ? lds[t - o] : 0;
    __syncthreads();
    lds[t] += x;
    __syncthreads();
  }
  if (t < nb) bs[t] = lds[t];
}

__global__ __launch_bounds__(256)
void scan_c_kernel(int* __restrict__ out, int n, const int* __restrict__ bs) {
  int i = blockIdx.x * blockDim.x + threadIdx.x;
  if (i >= n) return;
  int b = i >> 10;
  if (b > 0) out[i] += bs[b - 1];
}

__global__ __launch_bounds__(256)
void fill_kernel(const int* __restrict__ src, const int* __restrict__ dst,
                 int E, int ET, const int* __restrict__ rowptr,
                 int* __restrict__ cursor, int* __restrict__ csr_src) {
  int i = blockIdx.x * blockDim.x + threadIdx.x;
  if (i >= ET) return;
  int s, d; edge_sd(src, dst, i, E, s, d);
  int pos = rowptr[d] + atomicAdd(cursor + d, 1);
  csr_src[pos] = s;
}

// ---------------- dense projection + fused alpha dot-products ----------------
// H[N,OUT_C] = A[N,K] @ W[K,OUT_C]; asN = H.a_src; adN = H.a_dst.
// 256 threads = 4 waves. Lane owns cols lane*4 (256-padded col space; Wpad
// zero-padded so pad lanes accumulate 0). Wave owns 16 rows; A values are
// same-address LDS broadcasts (conflict-free). Staging is pure
// global_load_lds (no VGPR round-trip, no spill): W tile = 20 x 1KB issues,
// A tile = 5 x 1KB issues. Single LDS buffer; __syncthreads drains vmcnt.
__global__ __launch_bounds__(256)
void gemm_ws_kernel(const float* __restrict__ A, const float* __restrict__ Wpad,
                    const float* __restrict__ a_src, const float* __restrict__ a_dst,
                    float* __restrict__ H, float* __restrict__ asN,
                    float* __restrict__ adN, int K, int N) {
  __shared__ float Ws[BKC][256];   // 20 KB
  __shared__ float As[BMB][BKC];   // 5 KB
  int t = threadIdx.x;
  int wave = t >> 6, lane = t & 63;
  int col = lane * 4;              // padded col space
  long row0 = (long)blockIdx.x * BMB;
  int wrow = wave * BMW;

  float4 acc[BMW];
  #pragma unroll
  for (int r = 0; r < BMW; ++r) acc[r] = make_float4(0.f, 0.f, 0.f, 0.f);

  const int nch = K / BKC;
  for (int ch = 0; ch < nch; ++ch) {
    const int kc = ch * BKC;
    // stage W: wave w loads tile rows 5w..5w+4 (one 1KB issue per row)
    #pragma unroll
    for (int j = 0; j < 5; ++j) {
      int r = wave * 5 + j;
      glds16(Wpad + (long)(kc + r) * 256 + col, &Ws[r][0]);
    }
    // stage A: 5 x 1KB issues; wave w does issue w, wave 0 also does issue 4
    {
      int f = wave * 64 + lane;          // float4 index in tile
      long row = row0 + f / 5;
      if (row >= N) row = N - 1;         // clamp (last block), stores masked
      glds16(A + row * K + kc + (f % 5) * 4, &As[0][0] + wave * 256);
    }
    if (wave == 0) {
      int f = 256 + lane;
      long row = row0 + f / 5;
      if (row >= N) row = N - 1;
      glds16(A + row * K + kc + (f % 5) * 4, &As[0][0] + 1024);
    }
    __syncthreads();   // emits s_waitcnt vmcnt(0) + barrier: tiles ready
    #pragma unroll
    for (int kk = 0; kk < BKC; kk += 4) {
      float4 w0 = *(float4*)&Ws[kk + 0][col];
      float4 w1 = *(float4*)&Ws[kk + 1][col];
      float4 w2 = *(float4*)&Ws[kk + 2][col];
      float4 w3 = *(float4*)&Ws[kk + 3][col];
      #pragma unroll
      for (int r = 0; r < BMW; ++r) {
        float4 a = *(float4*)&As[wrow + r][kk];   // wave-uniform broadcast
        acc[r].x += a.x * w0.x + a.y * w1.x + a.z * w2.x + a.w * w3.x;
        acc[r].y += a.x * w0.y + a.y * w1.y + a.z * w2.y + a.w * w3.y;
        acc[r].z += a.x * w0.z + a.y * w1.z + a.z * w2.z + a.w * w3.z;
        acc[r].w += a.x * w0.w + a.y * w1.w + a.z * w2.w + a.w * w3.w;
      }
    }
    __syncthreads();   // all waves done reading before next stage overwrites
  }

  // epilogue: H rows + fused alpha dot-products
  bool cok = col < OUT_C;
  #pragma unroll
  for (int r = 0; r < BMW; ++r) {
    long grow = row0 + wrow + r;
    if (cok && grow < N) *(float4*)(H + grow * OUT_C + col) = acc[r];
  }
  float4 vs = make_float4(0.f, 0.f, 0.f, 0.f);
  float4 vd = make_float4(0.f, 0.f, 0.f, 0.f);
  if (cok) {
    vs = *(const float4*)(a_src + col);
    vd = *(const float4*)(a_dst + col);
  }
  #pragma unroll
  for (int r = 0; r < BMW; ++r) {
    float ss = acc[r].x * vs.x + acc[r].y * vs.y + acc[r].z * vs.z + acc[r].w * vs.w;
    float sd = acc[r].x * vd.x + acc[r].y * vd.y + acc[r].z * vd.z + acc[r].w * vd.w;
    #pragma unroll
    for (int o = 32; o > 0; o >>= 1) {
      ss += __shfl_xor(ss, o);
      sd += __shfl_xor(sd, o);
    }
    long grow = row0 + wrow + r;
    if (lane == 0 && grow < N) { asN[grow] = ss; adN[grow] = sd; }
  }
}

// ---------------- fused segment-softmax + gather-aggregate + bias + relu ----
// One wave per destination node.
__global__ __launch_bounds__(256)
void gather_agg_kernel(const float* __restrict__ h, const float* __restrict__ asN,
                       const float* __restrict__ adN, const int* __restrict__ rowptr,
                       const int* __restrict__ csr_src, const float* __restrict__ bias,
                       float* __restrict__ out, int N) {
  int wid = (int)(((long)blockIdx.x * blockDim.x + threadIdx.x) >> 6);
  int lane = threadIdx.x & 63;
  if (wid >= N) return;
  int start = rowptr[wid], end = rowptr[wid + 1];
  float ad = adN[wid];

  // pass 1a: max over incoming edges
  float m = -1e30f;
  for (int j = start + lane; j < end; j += 64) {
    float sc = asN[csr_src[j]] + ad;
    sc = sc > 0.f ? sc : NEG_SLOPE * sc;
    m = fmaxf(m, sc);
  }
  for (int o = 32; o > 0; o >>= 1) m = fmaxf(m, __shfl_xor(m, o));
  // pass 1b: sum of exp
  float se = 0.f;
  for (int j = start + lane; j < end; j += 64) {
    float sc = asN[csr_src[j]] + ad;
    sc = sc > 0.f ? sc : NEG_SLOPE * sc;
    se += __expf(sc - m);
  }
  for (int o = 32; o > 0; o >>= 1) se += __shfl_xor(se, o);
  float inv = 1.0f / se;

  // pass 2: weighted gather-accumulate (all lanes walk edges together)
  float acc0 = 0.f, acc1 = 0.f, acc2 = 0.f, acc3 = 0.f;
  int c0 = lane, c1 = lane + 64, c2 = lane + 128, c3 = lane + 192;
  for (int j = start; j < end; ++j) {
    int s = csr_src[j];                 // broadcast read
    float sc = asN[s] + ad;
    sc = sc > 0.f ? sc : NEG_SLOPE * sc;
    float w = __expf(sc - m) * inv;
    const float* hrow = h + (long)s * OUT_C;
    acc0 += w * hrow[c0];
    acc1 += w * hrow[c1];
    acc2 += w * hrow[c2];
    if (c3 < OUT_C) acc3 += w * hrow[c3];
  }
  float* orow = out + (long)wid * OUT_C;
  orow[c0] = fmaxf(acc0 + bias[c0], 0.f);
  orow[c1] = fmaxf(acc1 + bias[c1], 0.f);
  orow[c2] = fmaxf(acc2 + bias[c2], 0.f);
  if (c3 < OUT_C) orow[c3] = fmaxf(acc3 + bias[c3], 0.f);
}

// ---------------- driver ----------------
static void run_layer(const float* xin, int K, const float* Wpad,
                      const float* a_s, const float* a_d, const float* b,
                      const int* rowptr, const int* csr_src, int N,
                      float* hbuf, float* asN, float* adN, float* outbuf,
                      hipStream_t stream) {
  gemm_ws_kernel<<<cdiv(N, BMB), 256, 0, stream>>>(xin, Wpad, a_s, a_d,
                                                   hbuf, asN, adN, K, N);
  gather_agg_kernel<<<cdiv((long)N * 64, 256), 256, 0, stream>>>(
      hbuf, asN, adN, rowptr, csr_src, b, outbuf, N);
}

extern "C" void kernel_launch(void* const* d_in, const int* in_sizes, int n_in,
                              void* d_out, int out_size, void* d_ws, size_t ws_size,
                              hipStream_t stream) {
  const float* x   = (const float*)d_in[0];
  const float* W0  = (const float*)d_in[1];
  const float* as0 = (const float*)d_in[2];
  const float* ad0 = (const float*)d_in[3];
  const float* b0  = (const float*)d_in[4];
  const float* W1  = (const float*)d_in[5];
  const float* as1 = (const float*)d_in[6];
  const float* ad1 = (const float*)d_in[7];
  const float* b1  = (const float*)d_in[8];
  const int*   ei  = (const int*)d_in[9];

  const int N  = in_sizes[0] / IN_C;
  const int E  = in_sizes[9] / 2;
  const int ET = E + N;
  const int* src = ei;
  const int* dst = ei + E;

  float* out = (float*)d_out;

  char* ws = (char*)d_ws;
  float* hbuf   = (float*)ws;                                  // N*OUT_C
  float* asN    = (float*)(ws + (size_t)N * OUT_C * 4);        // N
  float* adN    = asN + N;                                     // N
  int*   rowptr = (int*)(adN + N);                             // N+1
  int*   counts = rowptr + (N + 1);                            // N (also cursor)
  int*   bsums  = counts + N;                                  // 256
  int*   csrsrc = bsums + 256;                                 // ET
  // 16B-align the padded-W buffers (float4 accesses)
  size_t woff = ((size_t)(csrsrc + ET - (int*)ws) + 3) & ~(size_t)3;
  float* wpad0 = (float*)ws + woff;                            // IN_C*256
  float* wpad1 = wpad0 + (size_t)IN_C * 256;                   // OUT_C*256

  const int nb = cdiv(N, 1024);

  // ---- one-time: pad W matrices, build CSR (shared by both layers) ----
  padw_kernel<<<cdiv(IN_C * 64, 256), 256, 0, stream>>>(W0, wpad0, IN_C);
  padw_kernel<<<cdiv(OUT_C * 64, 256), 256, 0, stream>>>(W1, wpad1, OUT_C);
  zero_int_kernel<<<cdiv(N, 256), 256, 0, stream>>>(counts, N);
  hist_kernel<<<cdiv(ET, 256), 256, 0, stream>>>(src, dst, E, ET, counts);
  scan_a_kernel<<<nb, 256, 0, stream>>>(counts, N, rowptr + 1, bsums);
  scan_b_kernel<<<1, 256, 0, stream>>>(bsums, nb);
  scan_c_kernel<<<cdiv(N, 256), 256, 0, stream>>>(rowptr + 1, N, bsums);
  zero_int_kernel<<<1, 256, 0, stream>>>(rowptr, 1);
  zero_int_kernel<<<cdiv(N, 256), 256, 0, stream>>>(counts, N);  // reuse as cursor
  fill_kernel<<<cdiv(ET, 256), 256, 0, stream>>>(src, dst, E, ET, rowptr, counts, csrsrc);

  // ---- layer 0: x -> out ----
  run_layer(x, IN_C, wpad0, as0, ad0, b0, rowptr, csrsrc, N, hbuf, asN, adN, out, stream);
  // ---- layer 1: out -> out (gemm reads out before gather_agg rewrites it) ----
  run_layer(out, OUT_C, wpad1, as1, ad1, b1, rowptr, csrsrc, N, hbuf, asN, adN, out, stream);
}

// Round 3
// 1134.291 us; speedup vs baseline: 3.2091x; 1.1649x over previous
//
#include <hip/hip_runtime.h>

#define IN_C 300
#define OUT_C 200
#define NEG_SLOPE 0.2f

// W-stationary GEMM geometry
#define BMB 64   // rows per block (4 waves x 16)
#define BMW 16   // rows per wave
#define BKC 20   // K chunk (divides 300 and 200)

static inline int cdiv(long a, int b) { return (int)((a + b - 1) / b); }

// async global->LDS, 16B per lane. LDS dest = wave-uniform base + lane*16.
__device__ __forceinline__ void glds16(const float* g, float* l) {
  __builtin_amdgcn_global_load_lds(
      (const __attribute__((address_space(1))) void*)g,
      (__attribute__((address_space(3))) void*)l, 16, 0, 0);
}

// ---------------- utility ----------------
__global__ __launch_bounds__(256)
void zero_int_kernel(int* __restrict__ p, int n) {
  int i = blockIdx.x * blockDim.x + threadIdx.x;
  if (i < n) p[i] = 0;
}

__device__ __forceinline__ void edge_sd(const int* __restrict__ src,
                                        const int* __restrict__ dst,
                                        int i, int E, int& s, int& d) {
  if (i < E) { s = src[i]; d = dst[i]; } else { s = d = i - E; }
}

// pad W[K][200] -> Wpad[K][256] (cols 200..255 zero) for exact 1KB wave-issues
__global__ __launch_bounds__(256)
void padw_kernel(const float* __restrict__ W, float* __restrict__ Wpad, int K) {
  int idx = blockIdx.x * blockDim.x + threadIdx.x;  // float4 index over K*64
  if (idx >= K * 64) return;
  int k = idx >> 6, c = (idx & 63) * 4;
  float4 v = make_float4(0.f, 0.f, 0.f, 0.f);
  if (c < OUT_C) v = *(const float4*)(W + (long)k * OUT_C + c);
  *(float4*)(Wpad + (long)k * 256 + c) = v;
}

// ---------------- CSR build ----------------
__global__ __launch_bounds__(256)
void hist_kernel(const int* __restrict__ src, const int* __restrict__ dst,
                 int E, int ET, int* __restrict__ counts) {
  int i = blockIdx.x * blockDim.x + threadIdx.x;
  if (i >= ET) return;
  int s, d; edge_sd(src, dst, i, E, s, d);
  atomicAdd(counts + d, 1);
}

// inclusive scan, 1024 elems/block (256 thr x 4). out = rowptr+1.
__global__ __launch_bounds__(256)
void scan_a_kernel(const int* __restrict__ in, int n, int* __restrict__ out,
                   int* __restrict__ bsums) {
  __shared__ int lds[256];
  int t = threadIdx.x;
  int base = blockIdx.x * 1024 + t * 4;
  int v0 = (base + 0 < n) ? in[base + 0] : 0;
  int v1 = (base + 1 < n) ? in[base + 1] : 0;
  int v2 = (base + 2 < n) ? in[base + 2] : 0;
  int v3 = (base + 3 < n) ? in[base + 3] : 0;
  int s1 = v0 + v1, s2 = s1 + v2, s3 = s2 + v3;
  lds[t] = s3;
  __syncthreads();
  for (int o = 1; o < 256; o <<= 1) {
    int x = (t >= o) ? lds[t - o] : 0;
    __syncthreads();
    lds[t] += x;
    __syncthreads();
  }
  int pre = (t > 0) ? lds[t - 1] : 0;
  if (base + 0 < n) out[base + 0] = pre + v0;
  if (base + 1 < n) out[base + 1] = pre + s1;
  if (base + 2 < n) out[base + 2] = pre + s2;
  if (base + 3 < n) out[base + 3] = pre + s3;
  if (t == 255) bsums[blockIdx.x] = lds[255];
}

// single-block inclusive scan of block sums (nb <= 256)
__global__ __launch_bounds__(256)
void scan_b_kernel(int* __restrict__ bs, int nb) {
  __shared__ int lds[256];
  int t = threadIdx.x;
  lds[t] = (t < nb) ? bs[t] : 0;
  __syncthreads();
  for (int o = 1; o < 256; o <<= 1) {
    int x = (t >= o) ? lds[t - o] : 0;
    __syncthreads();
    lds[t] += x;
    __syncthreads();
  }
  if (t < nb) bs[t] = lds[t];
}

__global__ __launch_bounds__(256)
void scan_c_kernel(int* __restrict__ out, int n, const int* __restrict__ bs) {
  int i = blockIdx.x * blockDim.x + threadIdx.x;
  if (i >= n) return;
  int b = i >> 10;
  if (b > 0) out[i] += bs[b - 1];
}

__global__ __launch_bounds__(256)
void fill_kernel(const int* __restrict__ src, const int* __restrict__ dst,
                 int E, int ET, const int* __restrict__ rowptr,
                 int* __restrict__ cursor, int* __restrict__ csr_src) {
  int i = blockIdx.x * blockDim.x + threadIdx.x;
  if (i >= ET) return;
  int s, d; edge_sd(src, dst, i, E, s, d);
  int pos = rowptr[d] + atomicAdd(cursor + d, 1);
  csr_src[pos] = s;
}

// ---------------- dense projection + fused alpha dot-products ----------------
// H[N,OUT_C] = A[N,K] @ W[K,OUT_C]; asN = H.a_src; adN = H.a_dst.
// Double-buffered global_load_lds staging (one barrier per chunk; next-chunk
// loads fly under the current chunk's FMAs). Inner loop is pure fmaf chains
// (4 FMA per 4 MACs — no mul/add split). A reads are wave-uniform LDS
// broadcasts; W reads contiguous 16B/lane (conflict-free).
__global__ __launch_bounds__(256)
void gemm_ws_kernel(const float* __restrict__ A, const float* __restrict__ Wpad,
                    const float* __restrict__ a_src, const float* __restrict__ a_dst,
                    float* __restrict__ H, float* __restrict__ asN,
                    float* __restrict__ adN, int K, int N) {
  __shared__ float Ws[2][BKC][256];   // 2 x 20 KB
  __shared__ float As[2][BMB][BKC];   // 2 x 5 KB
  int t = threadIdx.x;
  int wave = t >> 6, lane = t & 63;
  int col = lane * 4;                 // padded col space
  long row0 = (long)blockIdx.x * BMB;
  int wrow = wave * BMW;

  // ---- hoisted staging pointers (advance per chunk; no per-chunk div) ----
  // W: wave stages tile rows 5w..5w+4; lane supplies 16B at +col.
  const float* sW = Wpad + (long)(wave * 5) * 256 + col;
  // A: issue index f covers tile float4 f -> row f/5, col (f%5)*4.
  int f0 = wave * 64 + lane;
  long ar0 = row0 + f0 / 5; if (ar0 >= N) ar0 = N - 1;   // clamp, stores masked
  const float* sA0 = A + ar0 * K + (f0 % 5) * 4;
  int f1 = 256 + lane;
  long ar1 = row0 + f1 / 5; if (ar1 >= N) ar1 = N - 1;
  const float* sA1 = A + ar1 * K + (f1 % 5) * 4;         // only wave 0 issues

  auto stage = [&](int buf) {
    #pragma unroll
    for (int j = 0; j < 5; ++j)
      glds16(sW + j * 256, &Ws[buf][wave * 5 + j][0]);
    glds16(sA0, &As[buf][0][0] + wave * 256);
    if (wave == 0) glds16(sA1, &As[buf][0][0] + 1024);
    sW += BKC * 256; sA0 += BKC; sA1 += BKC;
  };

  float4 acc[BMW];
  #pragma unroll
  for (int r = 0; r < BMW; ++r) acc[r] = make_float4(0.f, 0.f, 0.f, 0.f);

  const int nch = K / BKC;
  stage(0);
  int cur = 0;
  for (int ch = 0; ch < nch; ++ch) {
    __syncthreads();   // drains vmcnt: buf[cur] ready; prev compute done
    if (ch + 1 < nch) stage(cur ^ 1);   // in flight under this chunk's FMAs
    #pragma unroll
    for (int kk = 0; kk < BKC; kk += 4) {
      float4 w0 = *(float4*)&Ws[cur][kk + 0][col];
      float4 w1 = *(float4*)&Ws[cur][kk + 1][col];
      float4 w2 = *(float4*)&Ws[cur][kk + 2][col];
      float4 w3 = *(float4*)&Ws[cur][kk + 3][col];
      #pragma unroll
      for (int r = 0; r < BMW; ++r) {
        float4 a = *(float4*)&As[cur][wrow + r][kk];   // wave-uniform broadcast
        acc[r].x = fmaf(a.x, w0.x, acc[r].x);
        acc[r].x = fmaf(a.y, w1.x, acc[r].x);
        acc[r].x = fmaf(a.z, w2.x, acc[r].x);
        acc[r].x = fmaf(a.w, w3.x, acc[r].x);
        acc[r].y = fmaf(a.x, w0.y, acc[r].y);
        acc[r].y = fmaf(a.y, w1.y, acc[r].y);
        acc[r].y = fmaf(a.z, w2.y, acc[r].y);
        acc[r].y = fmaf(a.w, w3.y, acc[r].y);
        acc[r].z = fmaf(a.x, w0.z, acc[r].z);
        acc[r].z = fmaf(a.y, w1.z, acc[r].z);
        acc[r].z = fmaf(a.z, w2.z, acc[r].z);
        acc[r].z = fmaf(a.w, w3.z, acc[r].z);
        acc[r].w = fmaf(a.x, w0.w, acc[r].w);
        acc[r].w = fmaf(a.y, w1.w, acc[r].w);
        acc[r].w = fmaf(a.z, w2.w, acc[r].w);
        acc[r].w = fmaf(a.w, w3.w, acc[r].w);
      }
    }
    cur ^= 1;
  }

  // epilogue: H rows + fused alpha dot-products
  bool cok = col < OUT_C;
  #pragma unroll
  for (int r = 0; r < BMW; ++r) {
    long grow = row0 + wrow + r;
    if (cok && grow < N) *(float4*)(H + grow * OUT_C + col) = acc[r];
  }
  float4 vs = make_float4(0.f, 0.f, 0.f, 0.f);
  float4 vd = make_float4(0.f, 0.f, 0.f, 0.f);
  if (cok) {
    vs = *(const float4*)(a_src + col);
    vd = *(const float4*)(a_dst + col);
  }
  #pragma unroll
  for (int r = 0; r < BMW; ++r) {
    float ss = acc[r].x * vs.x + acc[r].y * vs.y + acc[r].z * vs.z + acc[r].w * vs.w;
    float sd = acc[r].x * vd.x + acc[r].y * vd.y + acc[r].z * vd.z + acc[r].w * vd.w;
    #pragma unroll
    for (int o = 32; o > 0; o >>= 1) {
      ss += __shfl_xor(ss, o);
      sd += __shfl_xor(sd, o);
    }
    long grow = row0 + wrow + r;
    if (lane == 0 && grow < N) { asN[grow] = ss; adN[grow] = sd; }
  }
}

// ---------------- fused segment-softmax + gather-aggregate + bias + relu ----
// One wave per destination node. Pass-2 edge walk unrolled x2 (2 h-rows in
// flight); normalization by 1/se deferred to the store.
__global__ __launch_bounds__(256)
void gather_agg_kernel(const float* __restrict__ h, const float* __restrict__ asN,
                       const float* __restrict__ adN, const int* __restrict__ rowptr,
                       const int* __restrict__ csr_src, const float* __restrict__ bias,
                       float* __restrict__ out, int N) {
  int wid = (int)(((long)blockIdx.x * blockDim.x + threadIdx.x) >> 6);
  int lane = threadIdx.x & 63;
  if (wid >= N) return;
  int start = rowptr[wid], end = rowptr[wid + 1];
  float ad = adN[wid];

  // pass 1a: max over incoming edges
  float m = -1e30f;
  for (int j = start + lane; j < end; j += 64) {
    float sc = asN[csr_src[j]] + ad;
    sc = sc > 0.f ? sc : NEG_SLOPE * sc;
    m = fmaxf(m, sc);
  }
  for (int o = 32; o > 0; o >>= 1) m = fmaxf(m, __shfl_xor(m, o));
  // pass 1b: sum of exp
  float se = 0.f;
  for (int j = start + lane; j < end; j += 64) {
    float sc = asN[csr_src[j]] + ad;
    sc = sc > 0.f ? sc : NEG_SLOPE * sc;
    se += __expf(sc - m);
  }
  for (int o = 32; o > 0; o >>= 1) se += __shfl_xor(se, o);
  float inv = 1.0f / se;

  // pass 2: weighted gather-accumulate, unnormalized; scale by inv at store
  float acc0 = 0.f, acc1 = 0.f, acc2 = 0.f, acc3 = 0.f;
  int c0 = lane, c1 = lane + 64, c2 = lane + 128, c3 = lane + 192;
  int j = start;
  for (; j + 2 <= end; j += 2) {
    int s0 = csr_src[j], s1 = csr_src[j + 1];
    float e0 = asN[s0] + ad, e1 = asN[s1] + ad;
    e0 = e0 > 0.f ? e0 : NEG_SLOPE * e0;
    e1 = e1 > 0.f ? e1 : NEG_SLOPE * e1;
    float w0 = __expf(e0 - m), w1 = __expf(e1 - m);
    const float* h0 = h + (long)s0 * OUT_C;
    const float* h1 = h + (long)s1 * OUT_C;
    acc0 = fmaf(w0, h0[c0], acc0); acc0 = fmaf(w1, h1[c0], acc0);
    acc1 = fmaf(w0, h0[c1], acc1); acc1 = fmaf(w1, h1[c1], acc1);
    acc2 = fmaf(w0, h0[c2], acc2); acc2 = fmaf(w1, h1[c2], acc2);
    if (c3 < OUT_C) { acc3 = fmaf(w0, h0[c3], acc3); acc3 = fmaf(w1, h1[c3], acc3); }
  }
  if (j < end) {
    int s0 = csr_src[j];
    float e0 = asN[s0] + ad;
    e0 = e0 > 0.f ? e0 : NEG_SLOPE * e0;
    float w0 = __expf(e0 - m);
    const float* h0 = h + (long)s0 * OUT_C;
    acc0 = fmaf(w0, h0[c0], acc0);
    acc1 = fmaf(w0, h0[c1], acc1);
    acc2 = fmaf(w0, h0[c2], acc2);
    if (c3 < OUT_C) acc3 = fmaf(w0, h0[c3], acc3);
  }
  float* orow = out + (long)wid * OUT_C;
  orow[c0] = fmaxf(fmaf(acc0, inv, bias[c0]), 0.f);
  orow[c1] = fmaxf(fmaf(acc1, inv, bias[c1]), 0.f);
  orow[c2] = fmaxf(fmaf(acc2, inv, bias[c2]), 0.f);
  if (c3 < OUT_C) orow[c3] = fmaxf(fmaf(acc3, inv, bias[c3]), 0.f);
}

// ---------------- driver ----------------
static void run_layer(const float* xin, int K, const float* Wpad,
                      const float* a_s, const float* a_d, const float* b,
                      const int* rowptr, const int* csr_src, int N,
                      float* hbuf, float* asN, float* adN, float* outbuf,
                      hipStream_t stream) {
  gemm_ws_kernel<<<cdiv(N, BMB), 256, 0, stream>>>(xin, Wpad, a_s, a_d,
                                                   hbuf, asN, adN, K, N);
  gather_agg_kernel<<<cdiv((long)N * 64, 256), 256, 0, stream>>>(
      hbuf, asN, adN, rowptr, csr_src, b, outbuf, N);
}

extern "C" void kernel_launch(void* const* d_in, const int* in_sizes, int n_in,
                              void* d_out, int out_size, void* d_ws, size_t ws_size,
                              hipStream_t stream) {
  const float* x   = (const float*)d_in[0];
  const float* W0  = (const float*)d_in[1];
  const float* as0 = (const float*)d_in[2];
  const float* ad0 = (const float*)d_in[3];
  const float* b0  = (const float*)d_in[4];
  const float* W1  = (const float*)d_in[5];
  const float* as1 = (const float*)d_in[6];
  const float* ad1 = (const float*)d_in[7];
  const float* b1  = (const float*)d_in[8];
  const int*   ei  = (const int*)d_in[9];

  const int N  = in_sizes[0] / IN_C;
  const int E  = in_sizes[9] / 2;
  const int ET = E + N;
  const int* src = ei;
  const int* dst = ei + E;

  float* out = (float*)d_out;

  char* ws = (char*)d_ws;
  float* hbuf   = (float*)ws;                                  // N*OUT_C
  float* asN    = (float*)(ws + (size_t)N * OUT_C * 4);        // N
  float* adN    = asN + N;                                     // N
  int*   rowptr = (int*)(adN + N);                             // N+1
  int*   counts = rowptr + (N + 1);                            // N (also cursor)
  int*   bsums  = counts + N;                                  // 256
  int*   csrsrc = bsums + 256;                                 // ET
  // 16B-align the padded-W buffers (float4 accesses)
  size_t woff = ((size_t)(csrsrc + ET - (int*)ws) + 3) & ~(size_t)3;
  float* wpad0 = (float*)ws + woff;                            // IN_C*256
  float* wpad1 = wpad0 + (size_t)IN_C * 256;                   // OUT_C*256

  const int nb = cdiv(N, 1024);

  // ---- one-time: pad W matrices, build CSR (shared by both layers) ----
  padw_kernel<<<cdiv(IN_C * 64, 256), 256, 0, stream>>>(W0, wpad0, IN_C);
  padw_kernel<<<cdiv(OUT_C * 64, 256), 256, 0, stream>>>(W1, wpad1, OUT_C);
  zero_int_kernel<<<cdiv(N, 256), 256, 0, stream>>>(counts, N);
  hist_kernel<<<cdiv(ET, 256), 256, 0, stream>>>(src, dst, E, ET, counts);
  scan_a_kernel<<<nb, 256, 0, stream>>>(counts, N, rowptr + 1, bsums);
  scan_b_kernel<<<1, 256, 0, stream>>>(bsums, nb);
  scan_c_kernel<<<cdiv(N, 256), 256, 0, stream>>>(rowptr + 1, N, bsums);
  zero_int_kernel<<<1, 256, 0, stream>>>(rowptr, 1);
  zero_int_kernel<<<cdiv(N, 256), 256, 0, stream>>>(counts, N);  // reuse as cursor
  fill_kernel<<<cdiv(ET, 256), 256, 0, stream>>>(src, dst, E, ET, rowptr, counts, csrsrc);

  // ---- layer 0: x -> out ----
  run_layer(x, IN_C, wpad0, as0, ad0, b0, rowptr, csrsrc, N, hbuf, asN, adN, out, stream);
  // ---- layer 1: out -> out (gemm reads out before gather_agg rewrites it) ----
  run_layer(out, OUT_C, wpad1, as1, ad1, b1, rowptr, csrsrc, N, hbuf, asN, adN, out, stream);
}